// Round 1
// baseline (133.175 us; speedup 1.0000x reference)
//
#include <hip/hip_runtime.h>

#define HW    262144      // 512*512
#define BNUM  4
#define NC    33          // labels 0..32
#define NI    32          // instance channels

#define NB     1024       // t-space bins
#define BSCALE 64.0f      // NB / TMAX (TMAX = 16)
#define EG     4096       // e-grid bins in scan
#define ESCALE 2048.0f    // EG / 2.0

typedef unsigned long long ull;

// ws layout in 32-bit words:
//   [0..4)        cntB[s]  pass-B arrival counters
//   [4]           cntF     finalize counter
//   [8..12)       fin[s]   per-sample losses
//   [16..524304)  private hists u32[s][128][NB]: (s*128+j)*NB + b
//   [524304.. )   partials float[s][128][168]
#define W_CNTB 0
#define W_CNTF 4
#define W_FINL 8
#define W_HIST 16
#define W_PART (W_HIST + BNUM * 128 * NB)
#define PJ 168            // padded words per block slot (165 used)
#define PS (128 * PJ)     // words per sample

// ---------------- Pass A: per-instance stats -> deterministic partials.
// Also zeroes the arrival/finalize counters (no separate memset dispatch).
__global__ void __launch_bounds__(256) stats_kernel(
    const float* __restrict__ emb, const float* __restrict__ sig,
    const int* __restrict__ gt, float* __restrict__ ws) {
  int s = blockIdx.y;          // sample
  int j = blockIdx.x;          // 0..127 block within sample
  int t = threadIdx.x;
  int w = t >> 6;
  __shared__ float acc[4][165];   // [wave][f*33+n], f: e0,e1,ss,ss2,cnt
  int bid = s * 128 + j;          // 0..511
  unsigned* wsu = (unsigned*)ws;
  if (bid == 0 && t < 16) wsu[t] = 0u;   // counters + fin
  for (int k = t; k < 4 * 165; k += 256) ((float*)acc)[k] = 0.f;
  __syncthreads();
  const float* e0p = emb + (size_t)s * 2 * HW;
  const float* e1p = e0p + HW;
  const float* sp  = sig + (size_t)s * HW;
  const int*   gp  = gt  + (size_t)s * HW;
  #pragma unroll
  for (int i = 0; i < 2; ++i) {
    int idx = j * 2048 + i * 1024 + t * 4;
    int4   lb = *(const int4*)(gp + idx);
    float4 x  = *(const float4*)(e0p + idx);
    float4 y  = *(const float4*)(e1p + idx);
    float4 sg = *(const float4*)(sp + idx);
#define ACC(L, X, Y, SG)                                                   \
    if (L > 0) {                                                           \
      atomicAdd(&acc[w][L], X);        atomicAdd(&acc[w][33 + L], Y);      \
      atomicAdd(&acc[w][66 + L], SG);  atomicAdd(&acc[w][99 + L], (SG)*(SG)); \
      atomicAdd(&acc[w][132 + L], 1.0f);                                   \
    }
    ACC(lb.x, x.x, y.x, sg.x)
    ACC(lb.y, x.y, y.y, sg.y)
    ACC(lb.z, x.z, y.z, sg.z)
    ACC(lb.w, x.w, y.w, sg.w)
#undef ACC
  }
  __syncthreads();
  if (t < 165) {
    float v = acc[0][t] + acc[1][t] + acc[2][t] + acc[3][t];
    ws[W_PART + s * PS + j * PJ + t] = v;   // plain store, unique slot
  }
}

// ---------------- Pass B+C fused: hist; last-arriving block per sample scans.
__global__ void __launch_bounds__(512) hist_scan_kernel(
    const float* __restrict__ emb, const int* __restrict__ gt,
    float* __restrict__ ws, float* __restrict__ out) {
  int s  = blockIdx.y;
  int lb = blockIdx.x;           // 0..127
  __shared__ unsigned hist[EG * 2];   // 32 KB; hist phase uses first NB*4 (16 KB)
  __shared__ float sums[165];
  __shared__ float4 cons[NC];
  __shared__ ull wsum[8];
  __shared__ float red[8];
  __shared__ float vart_s;
  __shared__ int flag;
  int t = threadIdx.x;
  int lane = t & 63, wid = t >> 6;
  for (int k = t; k < NB * 4; k += 512) hist[k] = 0u;
  // sum the 128 per-block partials for this sample (coalesced across t)
  if (t < 165) {
    const float* pp = ws + W_PART + s * PS + t;
    float sum = 0.f;
    #pragma unroll 8
    for (int j = 0; j < 128; ++j) sum += pp[j * PJ];
    sums[t] = sum;
  }
  __syncthreads();
  if (t >= 1 && t < NC) {
    float c = sums[132 + t];
    float4 C;
    if (c > 0.f) {
      float inv = 1.0f / c;
      float c0 = sums[t] * inv, c1 = sums[33 + t] * inv, sgm = sums[66 + t] * inv;
      float Q = 0.5f / (sgm * sgm) * BSCALE;
      C.x = Q; C.y = -2.0f * Q * c0; C.z = -2.0f * Q * c1;
      C.w = Q * (c0 * c0 + c1 * c1);
    } else {
      C.x = 0.f; C.y = 0.f; C.z = 0.f; C.w = (float)NB;  // lands in last bin, e~0
    }
    cons[t] = C;
  }
  __syncthreads();
  const float* e0p = emb + (size_t)s * 2 * HW;
  const float* e1p = e0p + HW;
  const int*   gp  = gt  + (size_t)s * HW;
  int idx = lb * 2048 + t * 4;
  int4   lbl = *(const int4*)(gp + idx);
  float4 px  = *(const float4*)(e0p + idx);
  float4 py  = *(const float4*)(e1p + idx);
  float4 ss;
  ss.x = fmaf(px.x, px.x, py.x * py.x);
  ss.y = fmaf(px.y, px.y, py.y * py.y);
  ss.z = fmaf(px.z, px.z, py.z * py.z);
  ss.w = fmaf(px.w, px.w, py.w * py.w);
  unsigned* hr = hist + (t & 3);
  // positive-item correction: the n-loop below adds 1 (neg) for every item,
  // including the pixel's own instance; add 0xFFFF at the same bin so the
  // total becomes 0x10000 (one pos count, zero neg) for the pos item.
#define POSFIX(P0, P1, SV, L)                                            \
    if (L > 0) {                                                         \
      float4 C = cons[L];                                                \
      float bf = fmaf(C.x, SV, fmaf(C.y, P0, fmaf(C.z, P1, C.w)));       \
      int ib = min((int)bf, NB - 1);                                     \
      atomicAdd(&hr[ib << 2], 0xFFFFu);                                  \
    }
  POSFIX(px.x, py.x, ss.x, lbl.x)
  POSFIX(px.y, py.y, ss.y, lbl.y)
  POSFIX(px.z, py.z, ss.z, lbl.z)
  POSFIX(px.w, py.w, ss.w, lbl.w)
#undef POSFIX
  #pragma unroll 4
  for (int n = 1; n <= NI; ++n) {
    float4 C = cons[n];
    // branchless: clamp to last bin; t>=16 negs have e~2e-7, processed last
    // in the descending scan where p==P already -> contribution ~0.
#define ITEM(P0, P1, SV)                                               \
    {                                                                  \
      float bf = fmaf(C.x, SV, fmaf(C.y, P0, fmaf(C.z, P1, C.w)));     \
      int ib = min((int)bf, NB - 1);                                   \
      atomicAdd(&hr[ib << 2], 1u);                                     \
    }
    ITEM(px.x, py.x, ss.x)
    ITEM(px.y, py.y, ss.y)
    ITEM(px.z, py.z, ss.z)
    ITEM(px.w, py.w, ss.w)
#undef ITEM
  }
  __syncthreads();
  // flush to this block's PRIVATE global slot: plain agent-scope stores,
  // no RMW, no same-address contention (was 0.5M u64 atomics, 128-way).
  unsigned* gh = (unsigned*)ws + W_HIST + (s * 128 + lb) * NB;
  for (int k = t; k < NB; k += 512) {
    unsigned v = hist[k * 4] + hist[k * 4 + 1] + hist[k * 4 + 2] + hist[k * 4 + 3];
    __hip_atomic_store(&gh[k], v, __ATOMIC_RELAXED, __HIP_MEMORY_SCOPE_AGENT);
  }
  __syncthreads();
  if (t == 0) {
    __threadfence();   // release our slot stores before arrival
    flag = (__hip_atomic_fetch_add((unsigned*)ws + W_CNTB + s, 1u,
              __ATOMIC_ACQ_REL, __HIP_MEMORY_SCOPE_AGENT) == 127u);
  }
  __syncthreads();
  if (!flag) return;

  // ================= scan phase (one block per sample) =================
  unsigned* ep = hist;
  unsigned* en = hist + EG;
  for (int k = t; k < 2 * EG; k += 512) hist[k] = 0u;
  if (wid == 0) {   // pooled variance: vart = S_total * (sum 1/c) / NI
    float S = 0.f, rcp = 0.f;
    if (lane >= 1 && lane < NC) {
      float c = sums[132 + lane];
      if (c > 0.f) {
        float sg = sums[66 + lane] / c;
        S = sums[99 + lane] - c * sg * sg;
        rcp = 1.0f / c;
      }
    }
    for (int o = 32; o; o >>= 1) {
      S   += __shfl_down(S, o);
      rcp += __shfl_down(rcp, o);
    }
    if (lane == 0) vart_s = S * rcp / (float)NI;
  }
  __syncthreads();
  // sum the 128 private slots per bin (agent-scope loads), scatter to e-grid
  unsigned* ghs = (unsigned*)ws + W_HIST + s * 128 * NB;
  for (int b = t; b < NB; b += 512) {
    unsigned pos = 0, neg = 0;
    #pragma unroll 16
    for (int j = 0; j < 128; ++j) {
      unsigned v = __hip_atomic_load(&ghs[j * NB + b],
                     __ATOMIC_RELAXED, __HIP_MEMORY_SCOPE_AGENT);
      pos += v >> 16;
      neg += v & 0xFFFFu;
    }
    if (pos | neg) {
      float tc = ((float)b + 0.5f) * (1.0f / BSCALE);
      float ex = __expf(-tc);
      if (pos) {
        float e = 2.0f - 2.0f * ex;
        int k = (int)(e * ESCALE); if (k > EG - 1) k = EG - 1;
        atomicAdd(&ep[k], pos);
      }
      if (neg) {
        float e = 2.0f * ex;
        int k = (int)(e * ESCALE); if (k > EG - 1) k = EG - 1;
        atomicAdd(&en[k], neg);
      }
    }
  }
  __syncthreads();
  const int CH = EG / 512;  // 8
  int j0 = t * CH;
  unsigned np = 0, nn = 0;
  for (int k = 0; k < CH; ++k) {
    int b = EG - 1 - (j0 + k);
    np += ep[b]; nn += en[b];
  }
  ull v = ((ull)np << 32) | (ull)nn;
  ull inc = v;
  for (int o = 1; o < 64; o <<= 1) {
    ull u = __shfl_up(inc, o);
    if (lane >= o) inc += u;
  }
  if (lane == 63) wsum[wid] = inc;
  __syncthreads();
  ull offset = 0, total = 0;
  for (int i = 0; i < 8; ++i) {
    ull xr = wsum[i];
    if (i < wid) offset += xr;
    total += xr;
  }
  ull excl = offset + inc - v;
  float P = (float)(unsigned)(total >> 32);
  unsigned p = (unsigned)(excl >> 32), f = (unsigned)(excl & 0xFFFFFFFFu);
  float jprev = 1.0f - (P - (float)p) / (P + (float)f);
  float contrib = 0.f;
  for (int k = 0; k < CH; ++k) {
    int b = EG - 1 - (j0 + k);
    unsigned ap_ = ep[b], an_ = en[b];
    if (ap_ | an_) {
      p += ap_; f += an_;
      float j = 1.0f - (P - (float)p) / (P + (float)f);
      float e = ((float)b + 0.5f) * (2.0f / EG);
      contrib += e * (j - jprev);
      jprev = j;
    }
  }
  for (int o = 32; o; o >>= 1) contrib += __shfl_down(contrib, o);
  if (lane == 0) red[wid] = contrib;
  __syncthreads();
  if (t == 0) {
    float tot = 0.f;
    for (int i = 0; i < 8; ++i) tot += red[i];
    float loss = tot + vart_s;
    float* fin = ws + W_FINL;
    atomicExch(&fin[s], loss);
    __threadfence();
    unsigned old = atomicAdd((unsigned*)ws + W_CNTF, 1u);
    if (old == BNUM - 1) {
      float a = 0.f;
      for (int i = 0; i < BNUM; ++i) a += atomicAdd(&fin[i], 0.0f);
      out[0] = a * (1.0f / BNUM);
    }
  }
}

extern "C" void kernel_launch(void* const* d_in, const int* in_sizes, int n_in,
                              void* d_out, int out_size, void* d_ws, size_t ws_size,
                              hipStream_t stream) {
  const float* emb = (const float*)d_in[0];   // [4,2,512,512]
  const float* sig = (const float*)d_in[1];   // [4,1,512,512]
  const int*   gt  = (const int*)d_in[2];     // [4,1,512,512]
  float* out = (float*)d_out;
  float* ws  = (float*)d_ws;

  dim3 gA(128, BNUM);
  stats_kernel<<<gA, 256, 0, stream>>>(emb, sig, gt, ws);
  dim3 gB(128, BNUM);
  hist_scan_kernel<<<gB, 512, 0, stream>>>(emb, gt, ws, out);
}

// Round 3
// 129.654 us; speedup vs baseline: 1.0272x; 1.0272x over previous
//
#include <hip/hip_runtime.h>

#define HW    262144      // 512*512
#define BNUM  4
#define NC    33          // labels 0..32
#define NI    32          // instance channels

#define NB     1024       // t-space bins
#define BSCALE 64.0f      // NB / TMAX (TMAX = 16)
#define EG     4096       // e-grid bins in scan
#define ESCALE 2048.0f    // EG / 2.0

typedef unsigned long long ull;

// ws layout in 32-bit words:
//   [0..4)     cntC[s]   K3 per-sample arrival counters
//   [4]        cntF      finalize counter
//   [8..12)    fin[s]    per-sample losses
//   [12..16)   vart[s]   pooled variance term (written by K2)
//   [16..32784)          e-grid u32[s][2][EG] (pos then neg)
//   [32784..557072)      transposed private hists u32[s][b*128 + lb]
//   [557072..)           partials float[s][128][168]
#define W_CNTC 0
#define W_CNTF 4
#define W_FINL 8
#define W_VART 12
#define W_EGRID 16
#define W_HIST  (W_EGRID + BNUM * 2 * EG)       // 32784
#define W_PART  (W_HIST + BNUM * 128 * NB)      // 557072
#define PJ 168            // padded words per block slot (165 used)
#define PS (128 * PJ)     // words per sample

// ---------------- K1: per-instance stats -> deterministic partials.
// Also zeroes e-grid + counters (no separate memset dispatch).
__global__ void __launch_bounds__(256) stats_kernel(
    const float* __restrict__ emb, const float* __restrict__ sig,
    const int* __restrict__ gt, float* __restrict__ ws) {
  int s = blockIdx.y;          // sample
  int j = blockIdx.x;          // 0..127 block within sample
  int t = threadIdx.x;
  int w = t >> 6;
  __shared__ float acc[4][165];   // [wave][f*33+n], f: e0,e1,ss,ss2,cnt
  int bid = s * 128 + j;          // 0..511
  unsigned* wsu = (unsigned*)ws;
  if (t < 64) wsu[W_EGRID + bid * 64 + t] = 0u;   // 512*64 = 32768 words
  if (bid == 0 && t < 16) wsu[t] = 0u;            // counters + fin + vart
  for (int k = t; k < 4 * 165; k += 256) ((float*)acc)[k] = 0.f;
  __syncthreads();
  const float* e0p = emb + (size_t)s * 2 * HW;
  const float* e1p = e0p + HW;
  const float* sp  = sig + (size_t)s * HW;
  const int*   gp  = gt  + (size_t)s * HW;
  #pragma unroll
  for (int i = 0; i < 2; ++i) {
    int idx = j * 2048 + i * 1024 + t * 4;
    int4   lb = *(const int4*)(gp + idx);
    float4 x  = *(const float4*)(e0p + idx);
    float4 y  = *(const float4*)(e1p + idx);
    float4 sg = *(const float4*)(sp + idx);
#define ACC(L, X, Y, SG)                                                   \
    if (L > 0) {                                                           \
      atomicAdd(&acc[w][L], X);        atomicAdd(&acc[w][33 + L], Y);      \
      atomicAdd(&acc[w][66 + L], SG);  atomicAdd(&acc[w][99 + L], (SG)*(SG)); \
      atomicAdd(&acc[w][132 + L], 1.0f);                                   \
    }
    ACC(lb.x, x.x, y.x, sg.x)
    ACC(lb.y, x.y, y.y, sg.y)
    ACC(lb.z, x.z, y.z, sg.z)
    ACC(lb.w, x.w, y.w, sg.w)
#undef ACC
  }
  __syncthreads();
  if (t < 165) {
    float v = acc[0][t] + acc[1][t] + acc[2][t] + acc[3][t];
    ws[W_PART + s * PS + j * PJ + t] = v;   // plain store, unique slot
  }
}

// ---------------- K2: per-block LDS hist (8 sub-hists) -> transposed flush.
__global__ void __launch_bounds__(512) hist_kernel(
    const float* __restrict__ emb, const int* __restrict__ gt,
    float* __restrict__ ws) {
  int s  = blockIdx.y;
  int lb = blockIdx.x;           // 0..127
  int t = threadIdx.x;
  int lane = t & 63, wid = t >> 6;
  __shared__ unsigned hist[NB * 8];   // 32 KB, 8 interleaved sub-histograms
  __shared__ float sums2[2][165];
  __shared__ float sums[165];
  __shared__ float4 cons[NC];
  for (int k = t; k < NB * 8; k += 512) hist[k] = 0u;
  // 2-way latency-split reduction of the 128 per-block partials
  if (t < 330) {
    int r = (t >= 165) ? 1 : 0;
    int c = t - r * 165;
    const float* pp = ws + W_PART + s * PS + (r << 6) * PJ + c;
    float sum = 0.f;
    #pragma unroll 16
    for (int jj = 0; jj < 64; ++jj) sum += pp[jj * PJ];
    sums2[r][c] = sum;
  }
  __syncthreads();
  if (t < 165) sums[t] = sums2[0][t] + sums2[1][t];
  __syncthreads();
  if (t >= 1 && t < NC) {
    float c = sums[132 + t];
    float4 C;
    if (c > 0.f) {
      float inv = 1.0f / c;
      float c0 = sums[t] * inv, c1 = sums[33 + t] * inv, sgm = sums[66 + t] * inv;
      float Q = 0.5f / (sgm * sgm) * BSCALE;
      C.x = Q; C.y = -2.0f * Q * c0; C.z = -2.0f * Q * c1;
      C.w = Q * (c0 * c0 + c1 * c1);
    } else {
      C.x = 0.f; C.y = 0.f; C.z = 0.f; C.w = (float)NB;  // last bin, e~0
    }
    cons[t] = C;
  }
  if (lb == 0 && wid == 0) {   // pooled variance: vart = S_total*(sum 1/c)/NI
    float S = 0.f, rcp = 0.f;
    if (lane >= 1 && lane < NC) {
      float c = sums[132 + lane];
      if (c > 0.f) {
        float sg = sums[66 + lane] / c;
        S = sums[99 + lane] - c * sg * sg;
        rcp = 1.0f / c;
      }
    }
    for (int o = 32; o; o >>= 1) {
      S   += __shfl_down(S, o);
      rcp += __shfl_down(rcp, o);
    }
    if (lane == 0) ws[W_VART + s] = S * rcp / (float)NI;
  }
  __syncthreads();
  const float* e0p = emb + (size_t)s * 2 * HW;
  const float* e1p = e0p + HW;
  const int*   gp  = gt  + (size_t)s * HW;
  int idx = lb * 2048 + t * 4;
  int4   lbl = *(const int4*)(gp + idx);
  float4 px  = *(const float4*)(e0p + idx);
  float4 py  = *(const float4*)(e1p + idx);
  float4 ss;
  ss.x = fmaf(px.x, px.x, py.x * py.x);
  ss.y = fmaf(px.y, px.y, py.y * py.y);
  ss.z = fmaf(px.z, px.z, py.z * py.z);
  ss.w = fmaf(px.w, px.w, py.w * py.w);
  unsigned* hr = hist + (t & 7);
  // positive-item correction: the n-loop adds 1 (neg) for every item,
  // including the pixel's own instance; add 0xFFFF at the same bin so the
  // total becomes 0x10000 (one pos, zero neg) for the pos item.
#define POSFIX(P0, P1, SV, L)                                            \
    if (L > 0) {                                                         \
      float4 C = cons[L];                                                \
      float bf = fmaf(C.x, SV, fmaf(C.y, P0, fmaf(C.z, P1, C.w)));       \
      int ib = min((int)bf, NB - 1);                                     \
      atomicAdd(&hr[ib << 3], 0xFFFFu);                                  \
    }
  POSFIX(px.x, py.x, ss.x, lbl.x)
  POSFIX(px.y, py.y, ss.y, lbl.y)
  POSFIX(px.z, py.z, ss.z, lbl.z)
  POSFIX(px.w, py.w, ss.w, lbl.w)
#undef POSFIX
  #pragma unroll 4
  for (int n = 1; n <= NI; ++n) {
    float4 C = cons[n];
#define ITEM(P0, P1, SV)                                               \
    {                                                                  \
      float bf = fmaf(C.x, SV, fmaf(C.y, P0, fmaf(C.z, P1, C.w)));     \
      int ib = min((int)bf, NB - 1);                                   \
      atomicAdd(&hr[ib << 3], 1u);                                     \
    }
    ITEM(px.x, py.x, ss.x)
    ITEM(px.y, py.y, ss.y)
    ITEM(px.z, py.z, ss.z)
    ITEM(px.w, py.w, ss.w)
#undef ITEM
  }
  __syncthreads();
  // transposed flush: plain scattered stores, fire-and-forget, no RMW.
  unsigned* gh = (unsigned*)ws + W_HIST + s * (128 * NB);
  for (int k = t; k < NB; k += 512) {
    uint4 a = *(uint4*)&hist[k * 8];
    uint4 b = *(uint4*)&hist[k * 8 + 4];
    gh[k * 128 + lb] = a.x + a.y + a.z + a.w + b.x + b.y + b.z + b.w;
  }
}

// ---------------- K3: grid-parallel merge -> e-grid; last block scans.
__global__ void __launch_bounds__(512) merge_scan_kernel(
    float* __restrict__ ws, float* __restrict__ out) {
  int s  = blockIdx.y;
  int lb = blockIdx.x;           // 0..127
  int t = threadIdx.x;
  int lane = t & 63, wid = t >> 6;
  __shared__ unsigned eg[EG * 2];   // 32 KB (scan phase only)
  __shared__ ull wsum[8];
  __shared__ float red[8];
  __shared__ int flag;
  // merge: wave wid owns bin b = lb*8 + wid; 128 slots contiguous, coalesced
  unsigned* gh = (unsigned*)ws + W_HIST + s * (128 * NB);
  int b = lb * 8 + wid;
  unsigned v0 = gh[b * 128 + lane];
  unsigned v1 = gh[b * 128 + 64 + lane];
  ull pv = ((ull)((v0 >> 16) + (v1 >> 16)) << 32)
         | (ull)((v0 & 0xFFFFu) + (v1 & 0xFFFFu));
  for (int o = 32; o; o >>= 1) pv += __shfl_down(pv, o);
  if (lane == 0) {
    unsigned pos = (unsigned)(pv >> 32), neg = (unsigned)(pv & 0xFFFFFFFFu);
    unsigned* egp = (unsigned*)ws + W_EGRID + s * 2 * EG;
    unsigned* egn = egp + EG;
    float tc = ((float)b + 0.5f) * (1.0f / BSCALE);
    float ex = __expf(-tc);
    if (pos) {
      float e = 2.0f - 2.0f * ex;
      int k = (int)(e * ESCALE); if (k > EG - 1) k = EG - 1;
      atomicAdd(&egp[k], pos);
    }
    if (neg) {
      float e = 2.0f * ex;
      int k = (int)(e * ESCALE); if (k > EG - 1) k = EG - 1;
      atomicAdd(&egn[k], neg);
    }
  }
  __syncthreads();   // drains all waves' atomics (vmcnt(0) before barrier)
  if (t == 0) {
    __threadfence();
    flag = (atomicAdd((unsigned*)ws + W_CNTC + s, 1u) == 127u);
  }
  __syncthreads();
  if (!flag) return;

  // ================= scan phase (one block per sample) =================
  __threadfence();   // acquire: invalidate L2 so plain loads see LLC
  unsigned* egg = (unsigned*)ws + W_EGRID + s * 2 * EG;
  for (int k = t; k < 2 * EG; k += 512) eg[k] = egg[k];
  float vart = ws[W_VART + s];
  __syncthreads();
  unsigned* ep = eg;
  unsigned* en = eg + EG;
  const int CH = EG / 512;  // 8
  int j0 = t * CH;
  unsigned np = 0, nn = 0;
  for (int k = 0; k < CH; ++k) {
    int bb = EG - 1 - (j0 + k);
    np += ep[bb]; nn += en[bb];
  }
  ull v = ((ull)np << 32) | (ull)nn;
  ull inc = v;
  for (int o = 1; o < 64; o <<= 1) {
    ull u = __shfl_up(inc, o);
    if (lane >= o) inc += u;
  }
  if (lane == 63) wsum[wid] = inc;
  __syncthreads();
  ull offset = 0, total = 0;
  for (int i = 0; i < 8; ++i) {
    ull xr = wsum[i];
    if (i < wid) offset += xr;
    total += xr;
  }
  ull excl = offset + inc - v;
  float P = (float)(unsigned)(total >> 32);
  unsigned p = (unsigned)(excl >> 32), f = (unsigned)(excl & 0xFFFFFFFFu);
  float jprev = 1.0f - (P - (float)p) / (P + (float)f);
  float contrib = 0.f;
  for (int k = 0; k < CH; ++k) {
    int bb = EG - 1 - (j0 + k);
    unsigned ap_ = ep[bb], an_ = en[bb];
    if (ap_ | an_) {
      p += ap_; f += an_;
      float j = 1.0f - (P - (float)p) / (P + (float)f);
      float e = ((float)bb + 0.5f) * (2.0f / EG);
      contrib += e * (j - jprev);
      jprev = j;
    }
  }
  for (int o = 32; o; o >>= 1) contrib += __shfl_down(contrib, o);
  if (lane == 0) red[wid] = contrib;
  __syncthreads();
  if (t == 0) {
    float tot = 0.f;
    for (int i = 0; i < 8; ++i) tot += red[i];
    float loss = tot + vart;
    float* fin = ws + W_FINL;
    atomicExch(&fin[s], loss);
    __threadfence();
    unsigned old = atomicAdd((unsigned*)ws + W_CNTF, 1u);
    if (old == BNUM - 1) {
      float a = 0.f;
      for (int i = 0; i < BNUM; ++i) a += atomicAdd(&fin[i], 0.0f);
      out[0] = a * (1.0f / BNUM);
    }
  }
}

extern "C" void kernel_launch(void* const* d_in, const int* in_sizes, int n_in,
                              void* d_out, int out_size, void* d_ws, size_t ws_size,
                              hipStream_t stream) {
  const float* emb = (const float*)d_in[0];   // [4,2,512,512]
  const float* sig = (const float*)d_in[1];   // [4,1,512,512]
  const int*   gt  = (const int*)d_in[2];     // [4,1,512,512]
  float* out = (float*)d_out;
  float* ws  = (float*)d_ws;

  dim3 g(128, BNUM);
  stats_kernel<<<g, 256, 0, stream>>>(emb, sig, gt, ws);
  hist_kernel<<<g, 512, 0, stream>>>(emb, gt, ws);
  merge_scan_kernel<<<g, 512, 0, stream>>>(ws, out);
}